// Round 11
// baseline (2970.007 us; speedup 1.0000x reference)
//
#include <hip/hip_runtime.h>

// LSTM w/ hard-sigmoid gates. T=512, B=64, I=H=512.
// R11: wave-autonomous steps -- ZERO barriers in the 512-step loop.
// Evidence: R4/R6/R8/R10 all ~7000cy/step regardless of LDS/poll variants;
// the invariant was the barrier-coupled step skeleton. Here each h-wave owns
// consume->MFMA->update->publish for 8 j-columns x 8 batches end-to-end.
// Composition of proven primitives only:
//   - global per-wave monotonic flags, single-load poll, sc0sc1 (R4/R6)
//   - per-wave vmcnt-drain-then-flag (R6)
//   - LDS release/acquire handshakes (R10)
//   - parity-slot reuse justified by flag induction (R4)
// Row interleave (gate,jl)=(m&3, 8w+2*(m>>2)+(tile&1)): h-wave w's two C/D
// quads = gates (i,f,g,o) of adjacent (j,j+1) for batch lane&7 -> lane-local
// update, single packed-dword publish.
// Waves: x-waves 0-3 (w_ih, K-slice 128, run 1 step ahead, xpart parity-
// double-buffered + hdone back-flag); h-waves 4-7 (w_hh, K-slice 128,
// hpart single-buffer -- writer at t has proven peers finished t-1).
//
// Workspace: [0,4096)    : flags, 8 reps x 64 u32 -- memset 0 each launch
//            [4096,+128K): h double buffer [2][64][512] bf16

#define T_LEN 512
#define BATCH 64
#define ISZ   512
#define HSZ   512

#define NREP 8
#define WPR  16
#define BR   8
#define JW   32
#define NWG  (NREP * WPR)
#define NTHR 512

typedef __bf16 bf16x8 __attribute__((ext_vector_type(8)));
typedef float  f32x4  __attribute__((ext_vector_type(4)));
typedef float  f32x8  __attribute__((ext_vector_type(8)));
typedef int    i32x4  __attribute__((ext_vector_type(4)));

__device__ __forceinline__ bf16x8 cvt8(f32x4 a, f32x4 b) {
  f32x8 t;
  t[0]=a[0]; t[1]=a[1]; t[2]=a[2]; t[3]=a[3];
  t[4]=b[0]; t[5]=b[1]; t[6]=b[2]; t[7]=b[3];
  return __builtin_convertvector(t, bf16x8);   // v_cvt_pk_bf16_f32 pairs
}

__device__ __forceinline__ float fast_tanh(float v) {
  float e = __expf(2.0f * v);
  return 1.0f - 2.0f / (e + 1.0f);   // exact limits at +-inf
}

__device__ __forceinline__ float hsig(float v) {
  return fminf(fmaxf(0.2f * v + 0.5f, 0.0f), 1.0f);
}

__device__ __forceinline__ unsigned pack_bf16(float a, float b) {
  union { __bf16 h[2]; unsigned u; } p;
  p.h[0] = (__bf16)a; p.h[1] = (__bf16)b;
  return p.u;
}

// h loads: sc0 sc1 = bypass L1/L2, served at the device-coherent point
#define HLOAD(i, o)                                                        \
  asm volatile("global_load_dwordx4 %0, %1, off offset:" #o " sc0 sc1"     \
               : "=v"(hfrag[i]) : "v"(hr));
// x prefetch: plain cached loads, asm-pinned so they issue at the step tail
#define XLOAD(i, o)                                                        \
  asm volatile("global_load_dwordx4 %0, %1, off offset:" #o                \
               : "=v"(xpre[i]) : "v"(xr));

__global__ __launch_bounds__(NTHR, 2) void lstm_kernel(
    const float* __restrict__ x,      // [T][B][I]
    const float* __restrict__ h0,     // [B][H]
    const float* __restrict__ c0,     // [B][H]
    const float* __restrict__ w_ih,   // [4H][I]
    const float* __restrict__ w_hh,   // [4H][H]
    const float* __restrict__ b_ih,   // [4H]
    const float* __restrict__ b_hh,   // [4H]
    float* __restrict__ out,          // [T][B][H] ++ hn[B][H] ++ cn[B][H]
    unsigned* __restrict__ flags,     // [NREP][64] per-h-wave monotonic words
    __bf16* __restrict__ hbuf)        // [2][B][H]
{
  const int bid = blockIdx.x;
  const int rep = bid >> 4;           // 0..7
  const int wgi = bid & 15;           // 0..15
  const int B0  = rep * BR;
  const int J0  = wgi * JW;

  const int tid  = threadIdx.x;
  const int lane = tid & 63;
  const int wv   = tid >> 6;          // 0..7
  const int l15  = lane & 15;
  const int hic  = lane >> 4;         // 0..3
  const int lk   = hic << 3;
  const bool xw  = (wv < 4);          // x-waves 0-3, h-waves 4-7
  const int  w   = wv & 3;            // role index 0..3
  const int  K0  = w * 128;           // this wave's K-slice base
  const int  b8  = l15 & 7;           // batch row (lanes 8-15 duplicate 0-7)
  const int  wid = wgi * 4 + w;       // h-wave's flag slot in the replica

  unsigned* myf    = flags + rep * 64;
  unsigned* hbuf32 = (unsigned*)hbuf;

  // ---- weights -> registers: interleave row m of tile T:
  //      gate = m&3, jl = 8*(T>>1) + 2*(m>>2) + (T&1) ----
  bf16x8 wfrag[32];                   // [tile 0..7][ks 0..3]
  {
    const float* W = xw ? w_ih : w_hh;
#pragma unroll
    for (int tile = 0; tile < 8; ++tile) {
      const int grow = (l15 & 3) * HSZ
                     + J0 + 8 * (tile >> 1) + 2 * (l15 >> 2) + (tile & 1);
      const float* wp = W + (size_t)grow * 512 + K0 + lk;
#pragma unroll
      for (int ks = 0; ks < 4; ++ks) {
        f32x4 a = *(const f32x4*)(wp + ks * 32);
        f32x4 b = *(const f32x4*)(wp + ks * 32 + 4);
        wfrag[tile * 4 + ks] = cvt8(a, b);
      }
    }
  }

  // ---- h-wave lane-local output coords: tiles 2w,2w+1 -> j0 = J0+8w+2hic ----
  const int j0 = J0 + 8 * w + 2 * hic;
  const size_t brow = (size_t)(B0 + b8) * HSZ;

  f32x4 bias0, bias1;
#pragma unroll
  for (int r = 0; r < 4; ++r) {
    bias0[r] = b_ih[r * HSZ + j0]     + b_hh[r * HSZ + j0];
    bias1[r] = b_ih[r * HSZ + j0 + 1] + b_hh[r * HSZ + j0 + 1];
  }
  float cst0 = c0[brow + j0];
  float cst1 = c0[brow + j0 + 1];

  // ---- LDS: partials + intra-WG flags (no barriers in loop) ----
  __shared__ __align__(16) f32x4 lds_x[2 * 4 * 8 * 64];  // [par][src][tile][lane] 64KB
  __shared__ __align__(16) f32x4 lds_h[4 * 8 * 64];      // [src][tile][lane]      32KB
  __shared__ unsigned xflag[4];       // x-wave w -> h-waves, monotonic t+1
  __shared__ unsigned hflag[4];       // h-wave w -> peers,   monotonic t+1
  __shared__ unsigned hdone[4];       // h-wave w consumed xpart(t) -> t+1
  if (tid < 4) { xflag[tid] = 0; hflag[tid] = 0; hdone[tid] = 0; }

  // ---- x[0] prefetch (x-waves) ----
  f32x4 xpre[8];
  if (xw) {
    const float* xr = x + (size_t)(B0 + b8) * ISZ + K0 + lk;
    XLOAD(0, 0)   XLOAD(1, 16)  XLOAD(2, 128) XLOAD(3, 144)
    XLOAD(4, 256) XLOAD(5, 272) XLOAD(6, 384) XLOAD(7, 400)
  }

  // ---- h0 publish (h-waves, lane-local), per-wave drain + flag = 1 ----
  if (!xw) {
    float a = h0[brow + j0], b = h0[brow + j0 + 1];
    if (l15 < 8)
      __hip_atomic_store(&hbuf32[(brow + j0) >> 1], pack_bf16(a, b),
                         __ATOMIC_RELAXED, __HIP_MEMORY_SCOPE_AGENT);
    asm volatile("s_waitcnt vmcnt(0)" ::: "memory");
    if (lane == 0)
      __hip_atomic_store(&myf[wid], 1u, __ATOMIC_RELAXED, __HIP_MEMORY_SCOPE_AGENT);
  }
  __syncthreads();                    // one-time: LDS flag init visible

  for (int t = 0; t < T_LEN; ++t) {
    f32x4 acc[8];
#pragma unroll
    for (int i = 0; i < 8; ++i) acc[i] = (f32x4)(0.0f);

    if (xw) {
      // ---------- x-wave: runs ~1 step ahead, never touches global sync ----
      asm volatile("s_waitcnt vmcnt(0)" ::: "memory");   // x[t] arrived
      __builtin_amdgcn_sched_barrier(0);                 // rule #18
      bf16x8 bx[4];
#pragma unroll
      for (int ks = 0; ks < 4; ++ks) bx[ks] = cvt8(xpre[2 * ks], xpre[2 * ks + 1]);
#pragma unroll
      for (int tile = 0; tile < 8; ++tile)
#pragma unroll
        for (int ks = 0; ks < 4; ++ks)
          acc[tile] = __builtin_amdgcn_mfma_f32_16x16x32_bf16(
              wfrag[tile * 4 + ks], bx[ks], acc[tile], 0, 0, 0);

      // back-pressure: slot t&1 free once all h-waves consumed xpart(t-2)
      if (t >= 2) {
        const unsigned tgt = (unsigned)(t - 1);
        long g = 0;
        for (;;) {
          unsigned v = __hip_atomic_load(&hdone[lane & 3], __ATOMIC_ACQUIRE,
                                         __HIP_MEMORY_SCOPE_WORKGROUP);
          if (__all((int)(v >= tgt))) break;
          if (++g > (1L << 16)) break;   // safety: corrupt visibly, don't hang
        }
        asm volatile("" ::: "memory");
        __builtin_amdgcn_sched_barrier(0);
      }
#pragma unroll
      for (int tile = 0; tile < 8; ++tile)
        lds_x[(((t & 1) * 4 + w) * 8 + tile) * 64 + lane] = acc[tile];
      asm volatile("s_waitcnt lgkmcnt(0)" ::: "memory");
      if (lane == 0)
        __hip_atomic_store(&xflag[w], (unsigned)(t + 1),
                           __ATOMIC_RELEASE, __HIP_MEMORY_SCOPE_WORKGROUP);

      // prefetch x[t+1]
      if (t + 1 < T_LEN) {
        const float* xr = x + ((size_t)(t + 1) * BATCH + B0 + b8) * ISZ + K0 + lk;
        XLOAD(0, 0)   XLOAD(1, 16)  XLOAD(2, 128) XLOAD(3, 144)
        XLOAD(4, 256) XLOAD(5, 272) XLOAD(6, 384) XLOAD(7, 400)
      }
    } else {
      // ---------- h-wave: full consume->update->publish chain ----
      // 1. global poll: all 64 h-waves of the replica published h_t
      {
        const unsigned tgt = (unsigned)(t + 1);
        long g = 0;
        for (;;) {
          unsigned v = __hip_atomic_load(&myf[lane], __ATOMIC_RELAXED,
                                         __HIP_MEMORY_SCOPE_AGENT);
          if (__all((int)(v >= tgt))) break;
          __builtin_amdgcn_s_sleep(1);
          if (++g > (1L << 16)) break;   // safety: corrupt visibly, don't hang
        }
      }
      __builtin_amdgcn_sched_barrier(0);

      // 2. h_t K-slice load (2KB/wave unique, L3)
      const __bf16* hr = hbuf + (size_t)(t & 1) * BATCH * HSZ + brow + K0 + lk;
      i32x4 hfrag[4];
      HLOAD(0, 0) HLOAD(1, 64) HLOAD(2, 128) HLOAD(3, 192)
      asm volatile("s_waitcnt vmcnt(0)" ::: "memory");
      __builtin_amdgcn_sched_barrier(0);   // rule #18: MFMAs stay below wait

      // 3. K-slice MFMA for all 8 tiles
#pragma unroll
      for (int tile = 0; tile < 8; ++tile)
#pragma unroll
        for (int ks = 0; ks < 4; ++ks)
          acc[tile] = __builtin_amdgcn_mfma_f32_16x16x32_bf16(
              wfrag[tile * 4 + ks], __builtin_bit_cast(bf16x8, hfrag[ks]),
              acc[tile], 0, 0, 0);

      // 4. share h-partials (single buffer: writer at t has proven all peers
      //    finished step t-1 via the global poll -- induction as hbuf parity)
#pragma unroll
      for (int tile = 0; tile < 8; ++tile)
        lds_h[(w * 8 + tile) * 64 + lane] = acc[tile];
      asm volatile("s_waitcnt lgkmcnt(0)" ::: "memory");
      if (lane == 0)
        __hip_atomic_store(&hflag[w], (unsigned)(t + 1),
                           __ATOMIC_RELEASE, __HIP_MEMORY_SCOPE_WORKGROUP);

      // 5. wait peers (h) + x-waves (x), both LDS-local
      {
        const unsigned tgt = (unsigned)(t + 1);
        long g = 0;
        for (;;) {
          unsigned a = __hip_atomic_load(&hflag[lane & 3], __ATOMIC_ACQUIRE,
                                         __HIP_MEMORY_SCOPE_WORKGROUP);
          unsigned b = __hip_atomic_load(&xflag[lane & 3], __ATOMIC_ACQUIRE,
                                         __HIP_MEMORY_SCOPE_WORKGROUP);
          if (__all((int)(a >= tgt && b >= tgt))) break;
          if (++g > (1L << 16)) break;   // safety: corrupt visibly, don't hang
        }
      }
      asm volatile("" ::: "memory");
      __builtin_amdgcn_sched_barrier(0);

      // 6. reduce my 2 tiles (2w, 2w+1) across 4 x-srcs + 4 h-srcs
      f32x4 g0 = bias0, g1 = bias1;
#pragma unroll
      for (int s = 0; s < 4; ++s) {
        g0 += lds_x[(((t & 1) * 4 + s) * 8 + 2 * w) * 64 + lane];
        g1 += lds_x[(((t & 1) * 4 + s) * 8 + 2 * w + 1) * 64 + lane];
        g0 += lds_h[(s * 8 + 2 * w) * 64 + lane];
        g1 += lds_h[(s * 8 + 2 * w + 1) * 64 + lane];
      }

      // 7. lane-local cell update: g*[r] = gate r of (b8, j0(+1))
      float iv0 = hsig(g0[0]), fv0 = hsig(g0[1]), ov0 = hsig(g0[3]);
      float gv0 = fast_tanh(g0[2]);
      cst0 = fv0 * cst0 + iv0 * gv0;
      float hv0 = ov0 * fast_tanh(cst0);
      float iv1 = hsig(g1[0]), fv1 = hsig(g1[1]), ov1 = hsig(g1[3]);
      float gv1 = fast_tanh(g1[2]);
      cst1 = fv1 * cst1 + iv1 * gv1;
      float hv1 = ov1 * fast_tanh(cst1);

      // release x back-pressure (xpart(t) fully consumed into g0/g1)
      if (lane == 0)
        __hip_atomic_store(&hdone[w], (unsigned)(t + 1),
                           __ATOMIC_RELEASE, __HIP_MEMORY_SCOPE_WORKGROUP);

      // 8. publish h_{t+1} (one packed dword) + out, per-wave drain, flag
      if (l15 < 8) {
        __hip_atomic_store(
            &hbuf32[(size_t)((t + 1) & 1) * (BATCH * HSZ / 2) + ((brow + j0) >> 1)],
            pack_bf16(hv0, hv1), __ATOMIC_RELAXED, __HIP_MEMORY_SCOPE_AGENT);
        float2 hv; hv.x = hv0; hv.y = hv1;
        *(float2*)&out[(size_t)t * BATCH * HSZ + brow + j0] = hv;
        if (t == T_LEN - 1) {
          *(float2*)&out[(size_t)T_LEN * BATCH * HSZ + brow + j0] = hv;       // hn
          float2 cv; cv.x = cst0; cv.y = cst1;
          *(float2*)&out[(size_t)T_LEN * BATCH * HSZ + (size_t)BATCH * HSZ
                         + brow + j0] = cv;                                   // cn
        }
      }
      asm volatile("s_waitcnt vmcnt(0)" ::: "memory");
      if (lane == 0)
        __hip_atomic_store(&myf[wid], (unsigned)(t + 2),
                           __ATOMIC_RELAXED, __HIP_MEMORY_SCOPE_AGENT);
    }
  }
}

extern "C" void kernel_launch(void* const* d_in, const int* in_sizes, int n_in,
                              void* d_out, int out_size, void* d_ws, size_t ws_size,
                              hipStream_t stream) {
  const float* x    = (const float*)d_in[0];
  const float* h0   = (const float*)d_in[1];
  const float* c0   = (const float*)d_in[2];
  const float* w_ih = (const float*)d_in[3];
  const float* w_hh = (const float*)d_in[4];
  const float* b_ih = (const float*)d_in[5];
  const float* b_hh = (const float*)d_in[6];
  float* out = (float*)d_out;

  unsigned* flags = (unsigned*)d_ws;
  __bf16* hbuf    = (__bf16*)((char*)d_ws + 4096);
  // needs 4096 + 2*64*512*2 = ~132KB of workspace

  hipMemsetAsync(d_ws, 0, 4096, stream);  // zero flag words (ws is poisoned)

  hipLaunchKernelGGL(lstm_kernel, dim3(NWG), dim3(NTHR), 0, stream,
                     x, h0, c0, w_ih, w_hh, b_ih, b_hh, out, flags, hbuf);
}